// Round 13
// baseline (98.233 us; speedup 1.0000x reference)
//
#include <hip/hip_runtime.h>
#include <hip/hip_bf16.h>

// Problem constants (match reference)
#define T_TOK 8192
#define DDIM  1024
#define HDIM  512
#define NE    8
#define TPE   (T_TOK / NE)   // 1024 tokens per expert (static partition per reference)

typedef __attribute__((ext_vector_type(4))) float floatx4;
typedef __attribute__((ext_vector_type(8))) short bf16x8;

#define SBAR() __builtin_amdgcn_sched_barrier(0)

__device__ __forceinline__ unsigned short f2bf(float f) {
    union { float f; unsigned int u; } v;
    v.f = f;
    unsigned int u = v.u;
    unsigned int r = u + 0x7FFFu + ((u >> 16) & 1u);  // RNE
    return (unsigned short)(r >> 16);
}

// packed f32x2 -> bf16x2 (RNE), single instruction
__device__ __forceinline__ unsigned int cvt_pk_bf16(float lo, float hi) {
    unsigned int r;
    asm("v_cvt_pk_bf16_f32 %0, %1, %2" : "=v"(r) : "v"(lo), "v"(hi));
    return r;
}

// async global -> LDS, 16 bytes per lane (dest must be linear: base + lane*16)
__device__ __forceinline__ void gld_lds16(const void* g, void* l) {
    __builtin_amdgcn_global_load_lds(
        (const __attribute__((address_space(1))) unsigned int*)g,
        (__attribute__((address_space(3))) unsigned int*)l, 16, 0, 0);
}

// ---------------------------------------------------------------------------
// Kernel 0 (streaming): X*scale -> bf16 only (48 MB round trip).
// ---------------------------------------------------------------------------
__global__ __launch_bounds__(256)
void convert_x_kernel(const float* __restrict__ X, const float* __restrict__ S,
                      unsigned short* __restrict__ Xb)
{
    const int NTX = (T_TOK * DDIM) / 4;            // 2,097,152 float4 chunks
    const int stride = gridDim.x * blockDim.x;
    for (int i = blockIdx.x * blockDim.x + threadIdx.x; i < NTX; i += stride) {
        int row = i >> 8;            // D/4 = 256 chunks per row
        int c4  = i & 255;
        float4 v = reinterpret_cast<const float4*>(X)[i];
        float sc = S[row * (DDIM / 32) + (c4 >> 3)];
        ushort4 b;
        b.x = f2bf(v.x * sc); b.y = f2bf(v.y * sc);
        b.z = f2bf(v.z * sc); b.w = f2bf(v.w * sc);
        reinterpret_cast<ushort4*>(Xb)[i] = b;
    }
}

// XCD-aware swizzle for 512-block grids (512 % 8 == 0 -> bijective)
__device__ __forceinline__ int xcd_swizzle_512(int raw) {
    return (raw & 7) * 64 + (raw >> 3);
}

// LDS tile layout: [128 rows][8 slots of 16B]. Bank-conflict swizzle (T2/G21):
//   phys_slot = logical_slot ^ (row & 7)
//   - gld_lds path: LDS dest LINEAR, global SOURCE slot pre-permuted.
//   - reg-staged path: ds_write directly to the swizzled slot.
//   - ds_read applies the same XOR.

// ---------------------------------------------------------------------------
// Kernel 1: h = silu(Xb W1^T) * (Xb W3^T).
// A = Xb bf16 via gld_lds (sA double-buffered);
// B = W13 fp32 reg-staged depth-2 (rB0/rB1), cvt_pk -> swizzled ds_write into
//     a SINGLE-buffered sB (write-late makes the second buffer redundant).
// LDS = 32 + 16 = 48 KB -> 3 blocks/CU (12 waves) -- the occupancy lever.
// Phase t (buf = t&1):
//   STAGEA(t+1, buf^1)  [4 gld_lds]
//   LOADB(t+2)          [8 fp32 loads -> regs]
//   COMPUTE(t)          [reads sA[buf] + sB]
//   vmcnt(12)           [drains LOADB(t+1); leaves STAGEA(t+1)+LOADB(t+2)]
//   s_barrier           [all waves done READING sB]
//   WRITEB(t+1) -> sB
//   vmcnt(8) lgkmcnt(0) [drains STAGEA(t+1)+ds_writes; LOADB(t+2) airborne]
//   s_barrier
// ---------------------------------------------------------------------------
__global__ __launch_bounds__(256, 3)
void gemm1_silu_kernel(const unsigned short* __restrict__ Xb,
                       const float* __restrict__ W13,
                       __hip_bfloat16* __restrict__ Hout)
{
    const int bid = xcd_swizzle_512(blockIdx.x);
    const int e  = bid >> 6;
    const int mt = (bid >> 3) & 7;    // token tile (128 rows)
    const int nt = bid & 7;           // h tile (64 cols)
    const int tok0 = e * TPE + mt * 128;
    const float* __restrict__ We = W13 + (size_t)e * (2 * HDIM) * DDIM;

    __shared__ __hip_bfloat16 sA[2][128][64];
    __shared__ __hip_bfloat16 sB[128][64];          // single buffer

    const int tid  = threadIdx.x;
    const int lane = tid & 63;
    const int wave = tid >> 6;
    const int wr = wave >> 1;   // 0..1 (M half)
    const int wc = wave & 1;    // 0..1 (N: 32 cols each)
    const int lr = lane & 15;
    const int sw0 = ((lane >> 4) ^ (lane & 7));

    floatx4 acc1[4][2] = {};
    floatx4 acc3[4][2] = {};

    // staging geometry
    const int srow0 = (tid >> 3);                       // 0..31
    const int c8    = (tid & 7) * 8;                    // logical col chunk
    const int dcol  = (tid & 7) * 8;                    // A LDS linear dest
    const int gcol  = ((tid & 7) ^ (srow0 & 7)) * 8;    // A global pre-swz src
    const int swcol = gcol;                             // B swizzled ds_write slot

    float4 rB0[8], rB1[8];

    auto LOADB = [&](int kk, float4* rB) {   // 8 VM ops, fp32 W13 (w1|w3 rows)
        const int k0 = kk * 64;
        #pragma unroll
        for (int j = 0; j < 4; ++j) {
            int row = srow0 + j * 32;
            int wrow = (j < 2) ? (nt * 64 + row)                 // w1 rows
                               : (HDIM + nt * 64 + (row - 64));  // w3 rows
            const float* p = &We[(size_t)wrow * DDIM + k0 + c8];
            rB[2*j]   = *reinterpret_cast<const float4*>(p);
            rB[2*j+1] = *reinterpret_cast<const float4*>(p + 4);
        }
    };
    auto STAGEA = [&](int kk, int buf) {     // 4 VM ops (gld_lds)
        const int k0 = kk * 64;
        #pragma unroll
        for (int j = 0; j < 4; ++j) {
            int row = srow0 + j * 32;        // row&7 invariant under +32
            gld_lds16(&Xb[(size_t)(tok0 + row) * DDIM + k0 + gcol],
                      &sA[buf][row][dcol]);
        }
    };
    auto WRITEB = [&](const float4* rB) {    // cvt + swizzled ds_write -> sB
        #pragma unroll
        for (int j = 0; j < 4; ++j) {
            int row = srow0 + j * 32;
            uint4 w;
            w.x = cvt_pk_bf16(rB[2*j].x,   rB[2*j].y);
            w.y = cvt_pk_bf16(rB[2*j].z,   rB[2*j].w);
            w.z = cvt_pk_bf16(rB[2*j+1].x, rB[2*j+1].y);
            w.w = cvt_pk_bf16(rB[2*j+1].z, rB[2*j+1].w);
            *reinterpret_cast<uint4*>(&sB[row][swcol]) = w;
        }
    };
    auto COMPUTE_KS = [&](int buf, int ks) {
        const int rc = (sw0 ^ (ks << 2)) << 3;   // swizzled read col
        bf16x8 a[4], b1[2], b3[2];
        #pragma unroll
        for (int m = 0; m < 4; ++m)
            a[m] = *reinterpret_cast<const bf16x8*>(&sA[buf][wr * 64 + m * 16 + lr][rc]);
        #pragma unroll
        for (int n = 0; n < 2; ++n) {
            b1[n] = *reinterpret_cast<const bf16x8*>(&sB[wc * 32 + n * 16 + lr][rc]);
            b3[n] = *reinterpret_cast<const bf16x8*>(&sB[64 + wc * 32 + n * 16 + lr][rc]);
        }
        #pragma unroll
        for (int m = 0; m < 4; ++m)
            #pragma unroll
            for (int n = 0; n < 2; ++n) {
                acc1[m][n] = __builtin_amdgcn_mfma_f32_16x16x32_bf16(a[m], b1[n], acc1[m][n], 0, 0, 0);
                acc3[m][n] = __builtin_amdgcn_mfma_f32_16x16x32_bf16(a[m], b3[n], acc3[m][n], 0, 0, 0);
            }
    };

    // ---- prologue: VM order [LOADB(0) 8][STAGEA(0) 4][LOADB(1) 8]
    LOADB(0, rB0);  SBAR();
    STAGEA(0, 0);   SBAR();
    LOADB(1, rB1);  SBAR();
    asm volatile("s_waitcnt vmcnt(12)" ::: "memory");  // LOADB(0) done
    SBAR();
    WRITEB(rB0);    SBAR();                            // sB <- tile 0
    asm volatile("s_waitcnt vmcnt(8) lgkmcnt(0)" ::: "memory"); // STAGEA(0)+writes
    SBAR();
    __builtin_amdgcn_s_barrier();
    // entering steady state: outstanding VM = LOADB(1) [8]

    // ---- steady phases 0..13 (even/odd pairs; static rB names)
    for (int t = 0; t < DDIM / 64 - 2; t += 2) {        // t = 0,2,...,12
        // phase t (buf 0): sB holds tile t; rB1 holds tile t+1 (in flight)
        STAGEA(t + 1, 1);   SBAR();
        LOADB(t + 2, rB0);  SBAR();
        COMPUTE_KS(0, 0);
        COMPUTE_KS(0, 1);
        asm volatile("s_waitcnt vmcnt(12)" ::: "memory");  // LOADB(t+1) -> rB1 ready
        SBAR();
        __builtin_amdgcn_s_barrier();                      // sB read-done by all
        WRITEB(rB1);        SBAR();
        asm volatile("s_waitcnt vmcnt(8) lgkmcnt(0)" ::: "memory"); // STAGEA(t+1)
        SBAR();
        __builtin_amdgcn_s_barrier();
        // phase t+1 (buf 1): sB holds tile t+1; rB0 holds tile t+2 (in flight)
        STAGEA(t + 2, 0);   SBAR();
        LOADB(t + 3, rB1);  SBAR();
        COMPUTE_KS(1, 0);
        COMPUTE_KS(1, 1);
        asm volatile("s_waitcnt vmcnt(12)" ::: "memory");  // LOADB(t+2) -> rB0 ready
        SBAR();
        __builtin_amdgcn_s_barrier();
        WRITEB(rB0);        SBAR();
        asm volatile("s_waitcnt vmcnt(8) lgkmcnt(0)" ::: "memory"); // STAGEA(t+2)
        SBAR();
        __builtin_amdgcn_s_barrier();
    }

    // ---- phase 14 (buf 0): rB1 holds LOADB(15); no more LOADB
    STAGEA(15, 1);    SBAR();
    COMPUTE_KS(0, 0);
    COMPUTE_KS(0, 1);
    asm volatile("s_waitcnt vmcnt(4)" ::: "memory");   // LOADB(15) done
    SBAR();
    __builtin_amdgcn_s_barrier();
    WRITEB(rB1);      SBAR();
    asm volatile("s_waitcnt vmcnt(0) lgkmcnt(0)" ::: "memory"); // STAGEA(15)
    SBAR();
    __builtin_amdgcn_s_barrier();
    // ---- phase 15 (buf 1)
    COMPUTE_KS(1, 0);
    COMPUTE_KS(1, 1);

    // ---- epilogue: h = silu(h1) * h3 -> bf16
    const int hcol0 = nt * 64 + wc * 32;
    #pragma unroll
    for (int m = 0; m < 4; ++m) {
        #pragma unroll
        for (int n = 0; n < 2; ++n) {
            #pragma unroll
            for (int i = 0; i < 4; ++i) {
                int row = tok0 + wr * 64 + m * 16 + (lane >> 4) * 4 + i;
                int col = hcol0 + n * 16 + (lane & 15);
                float h1 = acc1[m][n][i];
                float h3 = acc3[m][n][i];
                float sig = 1.0f / (1.0f + __expf(-h1));
                Hout[(size_t)row * HDIM + col] = __float2bfloat16(h1 * sig * h3);
            }
        }
    }
}

// ---------------------------------------------------------------------------
// Kernel 2: out = h W2^T.  (round-11/12 form, near its HBM floor; unchanged)
// A = Hb bf16 via gld_lds; B = W2 fp32->bf16 reg-staged depth-2, write-late.
// ---------------------------------------------------------------------------
__global__ __launch_bounds__(256, 2)
void gemm2_kernel(const __hip_bfloat16* __restrict__ Hin,
                  const float* __restrict__ W2,
                  float* __restrict__ Out)
{
    const int bid = xcd_swizzle_512(blockIdx.x);
    const int e  = bid >> 6;
    const int nt = (bid >> 3) & 7;    // d tile -- major (W2 tile reused)
    const int mt = bid & 7;           // token tile -- fastest (stream Hb)
    const int tok0 = e * TPE + mt * 128;
    const float* __restrict__ We = W2 + (size_t)e * DDIM * HDIM;

    __shared__ __hip_bfloat16 sA[2][128][64];
    __shared__ __hip_bfloat16 sB[2][128][64];

    const int tid  = threadIdx.x;
    const int lane = tid & 63;
    const int wave = tid >> 6;
    const int wr = wave >> 1;
    const int wc = wave & 1;
    const int lr = lane & 15;
    const int sw0 = ((lane >> 4) ^ (lane & 7));

    floatx4 acc[4][4] = {};

    const int srow0 = (tid >> 3);
    const int c8    = (tid & 7) * 8;
    const int dcol  = (tid & 7) * 8;
    const int swcol = ((tid & 7) ^ (srow0 & 7)) * 8;

    float4 rB0[8], rB1[8];

    auto LOADB = [&](int kk, float4* rB) {  // 8 VM ops
        const int k0 = kk * 64;
        #pragma unroll
        for (int j = 0; j < 4; ++j) {
            int row = srow0 + j * 32;
            const float* p = &We[(size_t)(nt * 128 + row) * HDIM + k0 + c8];
            rB[2*j]   = *reinterpret_cast<const float4*>(p);
            rB[2*j+1] = *reinterpret_cast<const float4*>(p + 4);
        }
    };
    auto STAGEA = [&](int kk, int buf) {    // 4 VM ops (gld_lds)
        const int k0 = kk * 64;
        #pragma unroll
        for (int j = 0; j < 4; ++j) {
            int row = srow0 + j * 32;
            gld_lds16(&Hin[(size_t)(tok0 + row) * HDIM + k0 + swcol],
                      &sA[buf][row][dcol]);
        }
    };
    auto WRITEB = [&](int buf, const float4* rB) {
        #pragma unroll
        for (int j = 0; j < 4; ++j) {
            int row = srow0 + j * 32;
            uint4 w;
            w.x = cvt_pk_bf16(rB[2*j].x,   rB[2*j].y);
            w.y = cvt_pk_bf16(rB[2*j].z,   rB[2*j].w);
            w.z = cvt_pk_bf16(rB[2*j+1].x, rB[2*j+1].y);
            w.w = cvt_pk_bf16(rB[2*j+1].z, rB[2*j+1].w);
            *reinterpret_cast<uint4*>(&sB[buf][row][swcol]) = w;
        }
    };
    auto COMPUTE = [&](int buf) {
        #pragma unroll
        for (int ks = 0; ks < 2; ++ks) {
            const int rc = (sw0 ^ (ks << 2)) << 3;
            bf16x8 a[4], b[4];
            #pragma unroll
            for (int m = 0; m < 4; ++m)
                a[m] = *reinterpret_cast<const bf16x8*>(&sA[buf][wr * 64 + m * 16 + lr][rc]);
            #pragma unroll
            for (int n = 0; n < 4; ++n)
                b[n] = *reinterpret_cast<const bf16x8*>(&sB[buf][wc * 64 + n * 16 + lr][rc]);
            #pragma unroll
            for (int m = 0; m < 4; ++m)
                #pragma unroll
                for (int n = 0; n < 4; ++n)
                    acc[m][n] = __builtin_amdgcn_mfma_f32_16x16x32_bf16(a[m], b[n], acc[m][n], 0, 0, 0);
        }
    };

    // ---- prologue
    LOADB(0, rB0);  SBAR();
    STAGEA(0, 0);   SBAR();
    LOADB(1, rB1);  SBAR();
    asm volatile("s_waitcnt vmcnt(12)" ::: "memory");  // LOADB(0) done
    SBAR();
    WRITEB(0, rB0); SBAR();
    asm volatile("s_waitcnt vmcnt(8) lgkmcnt(0)" ::: "memory");
    SBAR();
    __builtin_amdgcn_s_barrier();

    // ---- steady phases 0..5
    for (int t = 0; t < HDIM / 64 - 2; t += 2) {        // t = 0,2,4
        // phase t (buf 0)
        STAGEA(t + 1, 1);   SBAR();
        LOADB(t + 2, rB0);  SBAR();
        COMPUTE(0);
        asm volatile("s_waitcnt vmcnt(12)" ::: "memory");  // LOADB(t+1) -> rB1
        SBAR();
        WRITEB(1, rB1);     SBAR();
        asm volatile("s_waitcnt vmcnt(8) lgkmcnt(0)" ::: "memory");
        SBAR();
        __builtin_amdgcn_s_barrier();
        // phase t+1 (buf 1)
        STAGEA(t + 2, 0);   SBAR();
        LOADB(t + 3, rB1);  SBAR();
        COMPUTE(1);
        asm volatile("s_waitcnt vmcnt(12)" ::: "memory");  // LOADB(t+2) -> rB0
        SBAR();
        WRITEB(0, rB0);     SBAR();
        asm volatile("s_waitcnt vmcnt(8) lgkmcnt(0)" ::: "memory");
        SBAR();
        __builtin_amdgcn_s_barrier();
    }

    // ---- phase 6 (buf 0): leftover LOADB(7) in rB1
    STAGEA(7, 1);   SBAR();
    COMPUTE(0);
    asm volatile("s_waitcnt vmcnt(4)" ::: "memory");   // LOADB(7) done
    SBAR();
    WRITEB(1, rB1); SBAR();
    asm volatile("s_waitcnt vmcnt(0) lgkmcnt(0)" ::: "memory");
    SBAR();
    __builtin_amdgcn_s_barrier();
    // ---- phase 7 (buf 1)
    COMPUTE(1);

    const int dcol0 = nt * 128 + wc * 64;
    #pragma unroll
    for (int m = 0; m < 4; ++m) {
        #pragma unroll
        for (int n = 0; n < 4; ++n) {
            #pragma unroll
            for (int i = 0; i < 4; ++i) {
                int row = tok0 + wr * 64 + m * 16 + (lane >> 4) * 4 + i;
                int col = dcol0 + n * 16 + (lane & 15);
                Out[(size_t)row * DDIM + col] = acc[m][n][i];
            }
        }
    }
}

extern "C" void kernel_launch(void* const* d_in, const int* in_sizes, int n_in,
                              void* d_out, int out_size, void* d_ws, size_t ws_size,
                              hipStream_t stream) {
    const float* X   = (const float*)d_in[0];   // (T, D) fp32
    const float* S   = (const float*)d_in[1];   // (T, D/32) fp32
    const float* W13 = (const float*)d_in[4];   // (E, 2H, D) fp32
    const float* W2  = (const float*)d_in[5];   // (E, D, H) fp32
    float* Out = (float*)d_out;                 // (T, D) fp32

    // workspace: Hb bf16 (T*H) = 8 MiB.
    // Xb (T*D bf16 = 16 MiB) lives in d_out's first half: gemm1 consumes it,
    // then gemm2 overwrites all of d_out with the final fp32 output.
    __hip_bfloat16* Hb = (__hip_bfloat16*)d_ws;
    unsigned short* Xb = (unsigned short*)d_out;

    convert_x_kernel<<<2048, 256, 0, stream>>>(X, S, Xb);
    gemm1_silu_kernel<<<NE * 8 * 8, 256, 0, stream>>>(Xb, W13, Hb);
    gemm2_kernel<<<NE * 8 * 8, 256, 0, stream>>>(Hb, W2, Out);
}

// Round 14
// 55.792 us; speedup vs baseline: 1.7607x; 1.7607x over previous
//
#include <hip/hip_runtime.h>
#include <hip/hip_bf16.h>

// Problem constants (match reference)
#define T_TOK 8192
#define DDIM  1024
#define HDIM  512
#define NE    8
#define TPE   (T_TOK / NE)   // 1024 tokens per expert (static partition per reference)

typedef __attribute__((ext_vector_type(4))) float floatx4;
typedef __attribute__((ext_vector_type(8))) short bf16x8;

#define SBAR() __builtin_amdgcn_sched_barrier(0)

__device__ __forceinline__ unsigned short f2bf(float f) {
    union { float f; unsigned int u; } v;
    v.f = f;
    unsigned int u = v.u;
    unsigned int r = u + 0x7FFFu + ((u >> 16) & 1u);  // RNE
    return (unsigned short)(r >> 16);
}

// packed f32x2 -> bf16x2 (RNE), single instruction
__device__ __forceinline__ unsigned int cvt_pk_bf16(float lo, float hi) {
    unsigned int r;
    asm("v_cvt_pk_bf16_f32 %0, %1, %2" : "=v"(r) : "v"(lo), "v"(hi));
    return r;
}

// async global -> LDS, 16 bytes per lane (dest must be linear: base + lane*16)
__device__ __forceinline__ void gld_lds16(const void* g, void* l) {
    __builtin_amdgcn_global_load_lds(
        (const __attribute__((address_space(1))) unsigned int*)g,
        (__attribute__((address_space(3))) unsigned int*)l, 16, 0, 0);
}

// ---------------------------------------------------------------------------
// Kernel 0 (streaming): X*scale -> bf16 only (48 MB round trip).
// ---------------------------------------------------------------------------
__global__ __launch_bounds__(256)
void convert_x_kernel(const float* __restrict__ X, const float* __restrict__ S,
                      unsigned short* __restrict__ Xb)
{
    const int NTX = (T_TOK * DDIM) / 4;            // 2,097,152 float4 chunks
    const int stride = gridDim.x * blockDim.x;
    for (int i = blockIdx.x * blockDim.x + threadIdx.x; i < NTX; i += stride) {
        int row = i >> 8;            // D/4 = 256 chunks per row
        int c4  = i & 255;
        float4 v = reinterpret_cast<const float4*>(X)[i];
        float sc = S[row * (DDIM / 32) + (c4 >> 3)];
        ushort4 b;
        b.x = f2bf(v.x * sc); b.y = f2bf(v.y * sc);
        b.z = f2bf(v.z * sc); b.w = f2bf(v.w * sc);
        reinterpret_cast<ushort4*>(Xb)[i] = b;
    }
}

// XCD-aware swizzle for 512-block grids (512 % 8 == 0 -> bijective)
__device__ __forceinline__ int xcd_swizzle_512(int raw) {
    return (raw & 7) * 64 + (raw >> 3);
}

// LDS tile layout: [128 rows][8 slots of 16B]. Bank-conflict swizzle (T2/G21):
//   phys_slot = logical_slot ^ (row & 7)
//   - gld_lds path: LDS dest LINEAR, global SOURCE slot pre-permuted.
//   - reg-staged path: ds_write directly to the swizzled slot.
//   - ds_read applies the same XOR.

// ---------------------------------------------------------------------------
// Kernel 1: h = silu(Xb W1^T) * (Xb W3^T).
// A = Xb bf16 via gld_lds (sA double-buffered);
// B = W13 fp32 reg-staged depth-2 (rB0/rB1), cvt_pk -> swizzled ds_write into
//     a SINGLE-buffered sB. LDS = 32 + 16 = 48 KB -> 3 blocks/CU (12 waves).
// __launch_bounds__(256, 2): rB0/rB1(64) + acc(64) need ~108 VGPR; the (256,3)
// variant capped at 84 and SPILLED (round 13: WRITE_SIZE 8->164 MB). VGPR 108
// allows 4 waves/SIMD, so occupancy is LDS-limited at 3 blocks/CU as intended.
// Phase t (buf = t&1):
//   STAGEA(t+1, buf^1); LOADB(t+2); COMPUTE(t);
//   vmcnt(12)  [LOADB(t+1) landed]; s_barrier [sB read-done];
//   WRITEB(t+1)->sB; vmcnt(8)+lgkmcnt(0); s_barrier
// ---------------------------------------------------------------------------
__global__ __launch_bounds__(256, 2)
void gemm1_silu_kernel(const unsigned short* __restrict__ Xb,
                       const float* __restrict__ W13,
                       __hip_bfloat16* __restrict__ Hout)
{
    const int bid = xcd_swizzle_512(blockIdx.x);
    const int e  = bid >> 6;
    const int mt = (bid >> 3) & 7;    // token tile (128 rows)
    const int nt = bid & 7;           // h tile (64 cols)
    const int tok0 = e * TPE + mt * 128;
    const float* __restrict__ We = W13 + (size_t)e * (2 * HDIM) * DDIM;

    __shared__ __hip_bfloat16 sA[2][128][64];
    __shared__ __hip_bfloat16 sB[128][64];          // single buffer

    const int tid  = threadIdx.x;
    const int lane = tid & 63;
    const int wave = tid >> 6;
    const int wr = wave >> 1;   // 0..1 (M half)
    const int wc = wave & 1;    // 0..1 (N: 32 cols each)
    const int lr = lane & 15;
    const int sw0 = ((lane >> 4) ^ (lane & 7));

    floatx4 acc1[4][2] = {};
    floatx4 acc3[4][2] = {};

    // staging geometry
    const int srow0 = (tid >> 3);                       // 0..31
    const int c8    = (tid & 7) * 8;                    // logical col chunk
    const int dcol  = (tid & 7) * 8;                    // A LDS linear dest
    const int gcol  = ((tid & 7) ^ (srow0 & 7)) * 8;    // A global pre-swz src
    const int swcol = gcol;                             // B swizzled ds_write slot

    float4 rB0[8], rB1[8];

    auto LOADB = [&](int kk, float4* rB) {   // 8 VM ops, fp32 W13 (w1|w3 rows)
        const int k0 = kk * 64;
        #pragma unroll
        for (int j = 0; j < 4; ++j) {
            int row = srow0 + j * 32;
            int wrow = (j < 2) ? (nt * 64 + row)                 // w1 rows
                               : (HDIM + nt * 64 + (row - 64));  // w3 rows
            const float* p = &We[(size_t)wrow * DDIM + k0 + c8];
            rB[2*j]   = *reinterpret_cast<const float4*>(p);
            rB[2*j+1] = *reinterpret_cast<const float4*>(p + 4);
        }
    };
    auto STAGEA = [&](int kk, int buf) {     // 4 VM ops (gld_lds)
        const int k0 = kk * 64;
        #pragma unroll
        for (int j = 0; j < 4; ++j) {
            int row = srow0 + j * 32;        // row&7 invariant under +32
            gld_lds16(&Xb[(size_t)(tok0 + row) * DDIM + k0 + gcol],
                      &sA[buf][row][dcol]);
        }
    };
    auto WRITEB = [&](const float4* rB) {    // cvt + swizzled ds_write -> sB
        #pragma unroll
        for (int j = 0; j < 4; ++j) {
            int row = srow0 + j * 32;
            uint4 w;
            w.x = cvt_pk_bf16(rB[2*j].x,   rB[2*j].y);
            w.y = cvt_pk_bf16(rB[2*j].z,   rB[2*j].w);
            w.z = cvt_pk_bf16(rB[2*j+1].x, rB[2*j+1].y);
            w.w = cvt_pk_bf16(rB[2*j+1].z, rB[2*j+1].w);
            *reinterpret_cast<uint4*>(&sB[row][swcol]) = w;
        }
    };
    auto COMPUTE_KS = [&](int buf, int ks) {
        const int rc = (sw0 ^ (ks << 2)) << 3;   // swizzled read col
        bf16x8 a[4], b1[2], b3[2];
        #pragma unroll
        for (int m = 0; m < 4; ++m)
            a[m] = *reinterpret_cast<const bf16x8*>(&sA[buf][wr * 64 + m * 16 + lr][rc]);
        #pragma unroll
        for (int n = 0; n < 2; ++n) {
            b1[n] = *reinterpret_cast<const bf16x8*>(&sB[wc * 32 + n * 16 + lr][rc]);
            b3[n] = *reinterpret_cast<const bf16x8*>(&sB[64 + wc * 32 + n * 16 + lr][rc]);
        }
        #pragma unroll
        for (int m = 0; m < 4; ++m)
            #pragma unroll
            for (int n = 0; n < 2; ++n) {
                acc1[m][n] = __builtin_amdgcn_mfma_f32_16x16x32_bf16(a[m], b1[n], acc1[m][n], 0, 0, 0);
                acc3[m][n] = __builtin_amdgcn_mfma_f32_16x16x32_bf16(a[m], b3[n], acc3[m][n], 0, 0, 0);
            }
    };

    // ---- prologue: VM order [LOADB(0) 8][STAGEA(0) 4][LOADB(1) 8]
    LOADB(0, rB0);  SBAR();
    STAGEA(0, 0);   SBAR();
    LOADB(1, rB1);  SBAR();
    asm volatile("s_waitcnt vmcnt(12)" ::: "memory");  // LOADB(0) done
    SBAR();
    WRITEB(rB0);    SBAR();                            // sB <- tile 0
    asm volatile("s_waitcnt vmcnt(8) lgkmcnt(0)" ::: "memory"); // STAGEA(0)+writes
    SBAR();
    __builtin_amdgcn_s_barrier();
    // entering steady state: outstanding VM = LOADB(1) [8]

    // ---- steady phases 0..13 (even/odd pairs; static rB names)
    for (int t = 0; t < DDIM / 64 - 2; t += 2) {        // t = 0,2,...,12
        // phase t (buf 0): sB holds tile t; rB1 holds tile t+1 (in flight)
        STAGEA(t + 1, 1);   SBAR();
        LOADB(t + 2, rB0);  SBAR();
        COMPUTE_KS(0, 0);
        COMPUTE_KS(0, 1);
        asm volatile("s_waitcnt vmcnt(12)" ::: "memory");  // LOADB(t+1) -> rB1 ready
        SBAR();
        __builtin_amdgcn_s_barrier();                      // sB read-done by all
        WRITEB(rB1);        SBAR();
        asm volatile("s_waitcnt vmcnt(8) lgkmcnt(0)" ::: "memory"); // STAGEA(t+1)
        SBAR();
        __builtin_amdgcn_s_barrier();
        // phase t+1 (buf 1): sB holds tile t+1; rB0 holds tile t+2 (in flight)
        STAGEA(t + 2, 0);   SBAR();
        LOADB(t + 3, rB1);  SBAR();
        COMPUTE_KS(1, 0);
        COMPUTE_KS(1, 1);
        asm volatile("s_waitcnt vmcnt(12)" ::: "memory");  // LOADB(t+2) -> rB0 ready
        SBAR();
        __builtin_amdgcn_s_barrier();
        WRITEB(rB0);        SBAR();
        asm volatile("s_waitcnt vmcnt(8) lgkmcnt(0)" ::: "memory"); // STAGEA(t+2)
        SBAR();
        __builtin_amdgcn_s_barrier();
    }

    // ---- phase 14 (buf 0): rB1 holds LOADB(15); no more LOADB
    STAGEA(15, 1);    SBAR();
    COMPUTE_KS(0, 0);
    COMPUTE_KS(0, 1);
    asm volatile("s_waitcnt vmcnt(4)" ::: "memory");   // LOADB(15) done
    SBAR();
    __builtin_amdgcn_s_barrier();
    WRITEB(rB1);      SBAR();
    asm volatile("s_waitcnt vmcnt(0) lgkmcnt(0)" ::: "memory"); // STAGEA(15)
    SBAR();
    __builtin_amdgcn_s_barrier();
    // ---- phase 15 (buf 1)
    COMPUTE_KS(1, 0);
    COMPUTE_KS(1, 1);

    // ---- epilogue: h = silu(h1) * h3 -> bf16
    const int hcol0 = nt * 64 + wc * 32;
    #pragma unroll
    for (int m = 0; m < 4; ++m) {
        #pragma unroll
        for (int n = 0; n < 2; ++n) {
            #pragma unroll
            for (int i = 0; i < 4; ++i) {
                int row = tok0 + wr * 64 + m * 16 + (lane >> 4) * 4 + i;
                int col = hcol0 + n * 16 + (lane & 15);
                float h1 = acc1[m][n][i];
                float h3 = acc3[m][n][i];
                float sig = 1.0f / (1.0f + __expf(-h1));
                Hout[(size_t)row * HDIM + col] = __float2bfloat16(h1 * sig * h3);
            }
        }
    }
}

// ---------------------------------------------------------------------------
// Kernel 2: out = h W2^T.  (round-11/12 form, near its HBM floor; unchanged)
// A = Hb bf16 via gld_lds; B = W2 fp32->bf16 reg-staged depth-2, write-late.
// ---------------------------------------------------------------------------
__global__ __launch_bounds__(256, 2)
void gemm2_kernel(const __hip_bfloat16* __restrict__ Hin,
                  const float* __restrict__ W2,
                  float* __restrict__ Out)
{
    const int bid = xcd_swizzle_512(blockIdx.x);
    const int e  = bid >> 6;
    const int nt = (bid >> 3) & 7;    // d tile -- major (W2 tile reused)
    const int mt = bid & 7;           // token tile -- fastest (stream Hb)
    const int tok0 = e * TPE + mt * 128;
    const float* __restrict__ We = W2 + (size_t)e * DDIM * HDIM;

    __shared__ __hip_bfloat16 sA[2][128][64];
    __shared__ __hip_bfloat16 sB[2][128][64];

    const int tid  = threadIdx.x;
    const int lane = tid & 63;
    const int wave = tid >> 6;
    const int wr = wave >> 1;
    const int wc = wave & 1;
    const int lr = lane & 15;
    const int sw0 = ((lane >> 4) ^ (lane & 7));

    floatx4 acc[4][4] = {};

    const int srow0 = (tid >> 3);
    const int c8    = (tid & 7) * 8;
    const int dcol  = (tid & 7) * 8;
    const int swcol = ((tid & 7) ^ (srow0 & 7)) * 8;

    float4 rB0[8], rB1[8];

    auto LOADB = [&](int kk, float4* rB) {  // 8 VM ops
        const int k0 = kk * 64;
        #pragma unroll
        for (int j = 0; j < 4; ++j) {
            int row = srow0 + j * 32;
            const float* p = &We[(size_t)(nt * 128 + row) * HDIM + k0 + c8];
            rB[2*j]   = *reinterpret_cast<const float4*>(p);
            rB[2*j+1] = *reinterpret_cast<const float4*>(p + 4);
        }
    };
    auto STAGEA = [&](int kk, int buf) {    // 4 VM ops (gld_lds)
        const int k0 = kk * 64;
        #pragma unroll
        for (int j = 0; j < 4; ++j) {
            int row = srow0 + j * 32;
            gld_lds16(&Hin[(size_t)(tok0 + row) * HDIM + k0 + swcol],
                      &sA[buf][row][dcol]);
        }
    };
    auto WRITEB = [&](int buf, const float4* rB) {
        #pragma unroll
        for (int j = 0; j < 4; ++j) {
            int row = srow0 + j * 32;
            uint4 w;
            w.x = cvt_pk_bf16(rB[2*j].x,   rB[2*j].y);
            w.y = cvt_pk_bf16(rB[2*j].z,   rB[2*j].w);
            w.z = cvt_pk_bf16(rB[2*j+1].x, rB[2*j+1].y);
            w.w = cvt_pk_bf16(rB[2*j+1].z, rB[2*j+1].w);
            *reinterpret_cast<uint4*>(&sB[buf][row][swcol]) = w;
        }
    };
    auto COMPUTE = [&](int buf) {
        #pragma unroll
        for (int ks = 0; ks < 2; ++ks) {
            const int rc = (sw0 ^ (ks << 2)) << 3;
            bf16x8 a[4], b[4];
            #pragma unroll
            for (int m = 0; m < 4; ++m)
                a[m] = *reinterpret_cast<const bf16x8*>(&sA[buf][wr * 64 + m * 16 + lr][rc]);
            #pragma unroll
            for (int n = 0; n < 4; ++n)
                b[n] = *reinterpret_cast<const bf16x8*>(&sB[buf][wc * 64 + n * 16 + lr][rc]);
            #pragma unroll
            for (int m = 0; m < 4; ++m)
                #pragma unroll
                for (int n = 0; n < 4; ++n)
                    acc[m][n] = __builtin_amdgcn_mfma_f32_16x16x32_bf16(a[m], b[n], acc[m][n], 0, 0, 0);
        }
    };

    // ---- prologue
    LOADB(0, rB0);  SBAR();
    STAGEA(0, 0);   SBAR();
    LOADB(1, rB1);  SBAR();
    asm volatile("s_waitcnt vmcnt(12)" ::: "memory");  // LOADB(0) done
    SBAR();
    WRITEB(0, rB0); SBAR();
    asm volatile("s_waitcnt vmcnt(8) lgkmcnt(0)" ::: "memory");
    SBAR();
    __builtin_amdgcn_s_barrier();

    // ---- steady phases 0..5
    for (int t = 0; t < HDIM / 64 - 2; t += 2) {        // t = 0,2,4
        // phase t (buf 0)
        STAGEA(t + 1, 1);   SBAR();
        LOADB(t + 2, rB0);  SBAR();
        COMPUTE(0);
        asm volatile("s_waitcnt vmcnt(12)" ::: "memory");  // LOADB(t+1) -> rB1
        SBAR();
        WRITEB(1, rB1);     SBAR();
        asm volatile("s_waitcnt vmcnt(8) lgkmcnt(0)" ::: "memory");
        SBAR();
        __builtin_amdgcn_s_barrier();
        // phase t+1 (buf 1)
        STAGEA(t + 2, 0);   SBAR();
        LOADB(t + 3, rB1);  SBAR();
        COMPUTE(1);
        asm volatile("s_waitcnt vmcnt(12)" ::: "memory");  // LOADB(t+2) -> rB0
        SBAR();
        WRITEB(0, rB0);     SBAR();
        asm volatile("s_waitcnt vmcnt(8) lgkmcnt(0)" ::: "memory");
        SBAR();
        __builtin_amdgcn_s_barrier();
    }

    // ---- phase 6 (buf 0): leftover LOADB(7) in rB1
    STAGEA(7, 1);   SBAR();
    COMPUTE(0);
    asm volatile("s_waitcnt vmcnt(4)" ::: "memory");   // LOADB(7) done
    SBAR();
    WRITEB(1, rB1); SBAR();
    asm volatile("s_waitcnt vmcnt(0) lgkmcnt(0)" ::: "memory");
    SBAR();
    __builtin_amdgcn_s_barrier();
    // ---- phase 7 (buf 1)
    COMPUTE(1);

    const int dcol0 = nt * 128 + wc * 64;
    #pragma unroll
    for (int m = 0; m < 4; ++m) {
        #pragma unroll
        for (int n = 0; n < 4; ++n) {
            #pragma unroll
            for (int i = 0; i < 4; ++i) {
                int row = tok0 + wr * 64 + m * 16 + (lane >> 4) * 4 + i;
                int col = dcol0 + n * 16 + (lane & 15);
                Out[(size_t)row * DDIM + col] = acc[m][n][i];
            }
        }
    }
}

extern "C" void kernel_launch(void* const* d_in, const int* in_sizes, int n_in,
                              void* d_out, int out_size, void* d_ws, size_t ws_size,
                              hipStream_t stream) {
    const float* X   = (const float*)d_in[0];   // (T, D) fp32
    const float* S   = (const float*)d_in[1];   // (T, D/32) fp32
    const float* W13 = (const float*)d_in[4];   // (E, 2H, D) fp32
    const float* W2  = (const float*)d_in[5];   // (E, D, H) fp32
    float* Out = (float*)d_out;                 // (T, D) fp32

    // workspace: Hb bf16 (T*H) = 8 MiB.
    // Xb (T*D bf16 = 16 MiB) lives in d_out's first half: gemm1 consumes it,
    // then gemm2 overwrites all of d_out with the final fp32 output.
    __hip_bfloat16* Hb = (__hip_bfloat16*)d_ws;
    unsigned short* Xb = (unsigned short*)d_out;

    convert_x_kernel<<<2048, 256, 0, stream>>>(X, S, Xb);
    gemm1_silu_kernel<<<NE * 8 * 8, 256, 0, stream>>>(Xb, W13, Hb);
    gemm2_kernel<<<NE * 8 * 8, 256, 0, stream>>>(Hb, W2, Out);
}

// Round 15
// 54.402 us; speedup vs baseline: 1.8057x; 1.0256x over previous
//
#include <hip/hip_runtime.h>
#include <hip/hip_bf16.h>

// Problem constants (match reference)
#define T_TOK 8192
#define DDIM  1024
#define HDIM  512
#define NE    8
#define TPE   (T_TOK / NE)   // 1024 tokens per expert (static partition per reference)

typedef __attribute__((ext_vector_type(4))) float floatx4;
typedef __attribute__((ext_vector_type(8))) short bf16x8;

#define SBAR() __builtin_amdgcn_sched_barrier(0)

__device__ __forceinline__ unsigned short f2bf(float f) {
    union { float f; unsigned int u; } v;
    v.f = f;
    unsigned int u = v.u;
    unsigned int r = u + 0x7FFFu + ((u >> 16) & 1u);  // RNE
    return (unsigned short)(r >> 16);
}

// packed f32x2 -> bf16x2 (RNE), single instruction
__device__ __forceinline__ unsigned int cvt_pk_bf16(float lo, float hi) {
    unsigned int r;
    asm("v_cvt_pk_bf16_f32 %0, %1, %2" : "=v"(r) : "v"(lo), "v"(hi));
    return r;
}

// async global -> LDS, 16 bytes per lane (dest must be linear: base + lane*16)
__device__ __forceinline__ void gld_lds16(const void* g, void* l) {
    __builtin_amdgcn_global_load_lds(
        (const __attribute__((address_space(1))) unsigned int*)g,
        (__attribute__((address_space(3))) unsigned int*)l, 16, 0, 0);
}

// ---------------------------------------------------------------------------
// Kernel 0 (streaming): X*scale -> bf16 only (48 MB round trip).
// ---------------------------------------------------------------------------
__global__ __launch_bounds__(256)
void convert_x_kernel(const float* __restrict__ X, const float* __restrict__ S,
                      unsigned short* __restrict__ Xb)
{
    const int NTX = (T_TOK * DDIM) / 4;            // 2,097,152 float4 chunks
    const int stride = gridDim.x * blockDim.x;
    for (int i = blockIdx.x * blockDim.x + threadIdx.x; i < NTX; i += stride) {
        int row = i >> 8;            // D/4 = 256 chunks per row
        int c4  = i & 255;
        float4 v = reinterpret_cast<const float4*>(X)[i];
        float sc = S[row * (DDIM / 32) + (c4 >> 3)];
        ushort4 b;
        b.x = f2bf(v.x * sc); b.y = f2bf(v.y * sc);
        b.z = f2bf(v.z * sc); b.w = f2bf(v.w * sc);
        reinterpret_cast<ushort4*>(Xb)[i] = b;
    }
}

// XCD-aware swizzles (nwg % 8 == 0 -> bijective)
__device__ __forceinline__ int xcd_swizzle_512(int raw) {
    return (raw & 7) * 64 + (raw >> 3);
}
__device__ __forceinline__ int xcd_swizzle_256(int raw) {
    return (raw & 7) * 32 + (raw >> 3);
}

// LDS tile layout: [rows][8 slots of 16B]. Bank-conflict swizzle (T2/G21):
//   phys 16B-slot = logical_slot ^ (row & 7)
//   - gld_lds path: LDS dest LINEAR, global SOURCE slot pre-permuted.
//   - reg-staged path: ds_write directly to the swizzled slot.
//   - ds_read applies the same XOR.

// ---------------------------------------------------------------------------
// Kernel 1: h = silu(Xb W1^T) * (Xb W3^T).
// ROUND-15 CHANGE: BM 128 -> 256 (512 thr, 8 waves 4Mx2N). gemm1 is pinned at
// the L3-BW roofline (round-12 profile: 384 MB device reads / 39 us = 9.8 TB/s
// because the 6 MB XCD working set thrashes the 4 MB L2). Raising BM cuts the
// W13 re-read factor 8 -> 4: per-XCD traffic 48 -> 32 MB (-33%).
// A = Xb bf16 via gld_lds (sA dbuf 64 KB); B = W13 fp32 reg-staged depth-2
// (rB0/rB1, 4 float4 each), cvt_pk -> swizzled ds_write (sB dbuf 32 KB).
// LDS 96 KB -> 1 block/CU, 8 waves. Write-late single-barrier phase:
//   STAGEA(t+1,buf^1)[4] ; LOADB(t+2)[4] ; COMPUTE(t) ;
//   vmcnt(8)  [LOADB(t+1) landed] ; WRITEB(t+1) ;
//   vmcnt(4)+lgkmcnt(0) [STAGEA(t+1) done; LOADB(t+2) airborne] ; s_barrier
// grid = 8e * 4mt * 8nt = 256 blocks.
// ---------------------------------------------------------------------------
__global__ __launch_bounds__(512, 2)
void gemm1_silu_kernel(const unsigned short* __restrict__ Xb,
                       const float* __restrict__ W13,
                       __hip_bfloat16* __restrict__ Hout)
{
    const int bid = xcd_swizzle_256(blockIdx.x);
    const int e  = bid >> 5;
    const int mt = (bid >> 3) & 3;    // token tile (256 rows)
    const int nt = bid & 7;           // h tile (64 cols)
    const int tok0 = e * TPE + mt * 256;
    const float* __restrict__ We = W13 + (size_t)e * (2 * HDIM) * DDIM;

    __shared__ __hip_bfloat16 sA[2][256][64];   // 64 KB
    __shared__ __hip_bfloat16 sB[2][128][64];   // 32 KB

    const int tid  = threadIdx.x;
    const int lane = tid & 63;
    const int wave = tid >> 6;   // 0..7
    const int wr = wave >> 1;    // 0..3 (M quarter: 64 rows)
    const int wc = wave & 1;     // 0..1 (N: 32 cols each)
    const int lr = lane & 15;
    const int sw0 = ((lane >> 4) ^ (lane & 7));

    floatx4 acc1[4][2] = {};
    floatx4 acc3[4][2] = {};

    // A staging: 256x64 bf16 = 2048 x 16B chunks / 512 thr = 4 each
    const int srowA = tid >> 3;                          // 0..63
    const int dcolA = (tid & 7) * 8;                     // LDS linear dest
    const int gcolA = ((tid & 7) ^ (srowA & 7)) * 8;     // pre-swizzled source
    // B load: 128 rows x 16 float4 / 512 thr = 4 each
    const int srowB = tid >> 4;                          // 0..31
    const int f4    = tid & 15;                          // float4 slot in row
    const int bcol  = f4 * 4;                            // fp32 col

    float4 rB0[4], rB1[4];

    auto LOADB = [&](int kk, float4* rB) {   // 4 VM ops, fp32 W13 (w1|w3 rows)
        const int k0 = kk * 64;
        #pragma unroll
        for (int j = 0; j < 4; ++j) {
            int row = srowB + j * 32;        // 0..127; row&7 const under +32
            int wrow = (j < 2) ? (nt * 64 + row)                 // w1 rows
                               : (HDIM + nt * 64 + (row - 64));  // w3 rows
            rB[j] = *reinterpret_cast<const float4*>(
                        &We[(size_t)wrow * DDIM + k0 + bcol]);
        }
    };
    auto STAGEA = [&](int kk, int buf) {     // 4 VM ops (gld_lds)
        const int k0 = kk * 64;
        #pragma unroll
        for (int j = 0; j < 4; ++j) {
            int row = srowA + j * 64;        // row&7 const under +64
            gld_lds16(&Xb[(size_t)(tok0 + row) * DDIM + k0 + gcolA],
                      &sA[buf][row][dcolA]);
        }
    };
    auto WRITEB = [&](int buf, const float4* rB) {   // cvt + swizzled ds_write_b64
        #pragma unroll
        for (int j = 0; j < 4; ++j) {
            int row = srowB + j * 32;
            uint2 w;
            w.x = cvt_pk_bf16(rB[j].x, rB[j].y);
            w.y = cvt_pk_bf16(rB[j].z, rB[j].w);
            char* base = reinterpret_cast<char*>(&sB[buf][row][0]);
            int off = (((f4 >> 1) ^ (row & 7)) << 4) + ((f4 & 1) << 3);
            *reinterpret_cast<uint2*>(base + off) = w;
        }
    };
    auto COMPUTE_KS = [&](int buf, int ks) {
        const int rc = (sw0 ^ (ks << 2)) << 3;   // swizzled read col
        bf16x8 a[4], b1[2], b3[2];
        #pragma unroll
        for (int m = 0; m < 4; ++m)
            a[m] = *reinterpret_cast<const bf16x8*>(&sA[buf][wr * 64 + m * 16 + lr][rc]);
        #pragma unroll
        for (int n = 0; n < 2; ++n) {
            b1[n] = *reinterpret_cast<const bf16x8*>(&sB[buf][wc * 32 + n * 16 + lr][rc]);
            b3[n] = *reinterpret_cast<const bf16x8*>(&sB[buf][64 + wc * 32 + n * 16 + lr][rc]);
        }
        #pragma unroll
        for (int m = 0; m < 4; ++m)
            #pragma unroll
            for (int n = 0; n < 2; ++n) {
                acc1[m][n] = __builtin_amdgcn_mfma_f32_16x16x32_bf16(a[m], b1[n], acc1[m][n], 0, 0, 0);
                acc3[m][n] = __builtin_amdgcn_mfma_f32_16x16x32_bf16(a[m], b3[n], acc3[m][n], 0, 0, 0);
            }
    };

    // ---- prologue: VM order [LOADB(0) 4][STAGEA(0) 4][LOADB(1) 4]
    LOADB(0, rB0);  SBAR();
    STAGEA(0, 0);   SBAR();
    LOADB(1, rB1);  SBAR();
    asm volatile("s_waitcnt vmcnt(8)" ::: "memory");   // LOADB(0) done
    SBAR();
    WRITEB(0, rB0); SBAR();
    asm volatile("s_waitcnt vmcnt(4) lgkmcnt(0)" ::: "memory"); // STAGEA(0)+writes
    SBAR();
    __builtin_amdgcn_s_barrier();
    // entering steady state: outstanding VM = LOADB(1) [4]

    // ---- steady phases 0..13 (even/odd pairs; static rB names)
    for (int t = 0; t < DDIM / 64 - 2; t += 2) {        // t = 0,2,...,12
        // phase t (buf 0): rB1 holds tile t+1 (in flight)
        STAGEA(t + 1, 1);   SBAR();
        LOADB(t + 2, rB0);  SBAR();
        COMPUTE_KS(0, 0);
        COMPUTE_KS(0, 1);
        asm volatile("s_waitcnt vmcnt(8)" ::: "memory");  // LOADB(t+1) -> rB1 ready
        SBAR();
        WRITEB(1, rB1);     SBAR();
        asm volatile("s_waitcnt vmcnt(4) lgkmcnt(0)" ::: "memory"); // STAGEA(t+1)
        SBAR();
        __builtin_amdgcn_s_barrier();
        // phase t+1 (buf 1): rB0 holds tile t+2 (in flight)
        STAGEA(t + 2, 0);   SBAR();
        LOADB(t + 3, rB1);  SBAR();
        COMPUTE_KS(1, 0);
        COMPUTE_KS(1, 1);
        asm volatile("s_waitcnt vmcnt(8)" ::: "memory");  // LOADB(t+2) -> rB0 ready
        SBAR();
        WRITEB(0, rB0);     SBAR();
        asm volatile("s_waitcnt vmcnt(4) lgkmcnt(0)" ::: "memory"); // STAGEA(t+2)
        SBAR();
        __builtin_amdgcn_s_barrier();
    }

    // ---- phase 14 (buf 0): rB1 holds LOADB(15); no more LOADB
    STAGEA(15, 1);    SBAR();
    COMPUTE_KS(0, 0);
    COMPUTE_KS(0, 1);
    asm volatile("s_waitcnt vmcnt(4)" ::: "memory");   // LOADB(15) done
    SBAR();
    WRITEB(1, rB1);   SBAR();
    asm volatile("s_waitcnt vmcnt(0) lgkmcnt(0)" ::: "memory"); // STAGEA(15)
    SBAR();
    __builtin_amdgcn_s_barrier();
    // ---- phase 15 (buf 1)
    COMPUTE_KS(1, 0);
    COMPUTE_KS(1, 1);

    // ---- epilogue: h = silu(h1) * h3 -> bf16
    const int hcol0 = nt * 64 + wc * 32;
    #pragma unroll
    for (int m = 0; m < 4; ++m) {
        #pragma unroll
        for (int n = 0; n < 2; ++n) {
            #pragma unroll
            for (int i = 0; i < 4; ++i) {
                int row = tok0 + wr * 64 + m * 16 + (lane >> 4) * 4 + i;
                int col = hcol0 + n * 16 + (lane & 15);
                float h1 = acc1[m][n][i];
                float h3 = acc3[m][n][i];
                float sig = 1.0f / (1.0f + __expf(-h1));
                Hout[(size_t)row * HDIM + col] = __float2bfloat16(h1 * sig * h3);
            }
        }
    }
}

// ---------------------------------------------------------------------------
// Kernel 2: out = h W2^T.  (round-11..14 form, near its L2/HBM floor; unchanged)
// A = Hb bf16 via gld_lds; B = W2 fp32->bf16 reg-staged depth-2, write-late.
// ---------------------------------------------------------------------------
__global__ __launch_bounds__(256, 2)
void gemm2_kernel(const __hip_bfloat16* __restrict__ Hin,
                  const float* __restrict__ W2,
                  float* __restrict__ Out)
{
    const int bid = xcd_swizzle_512(blockIdx.x);
    const int e  = bid >> 6;
    const int nt = (bid >> 3) & 7;    // d tile -- major (W2 tile reused)
    const int mt = bid & 7;           // token tile -- fastest (stream Hb)
    const int tok0 = e * TPE + mt * 128;
    const float* __restrict__ We = W2 + (size_t)e * DDIM * HDIM;

    __shared__ __hip_bfloat16 sA[2][128][64];
    __shared__ __hip_bfloat16 sB[2][128][64];

    const int tid  = threadIdx.x;
    const int lane = tid & 63;
    const int wave = tid >> 6;
    const int wr = wave >> 1;
    const int wc = wave & 1;
    const int lr = lane & 15;
    const int sw0 = ((lane >> 4) ^ (lane & 7));

    floatx4 acc[4][4] = {};

    const int srow0 = (tid >> 3);
    const int c8    = (tid & 7) * 8;
    const int dcol  = (tid & 7) * 8;
    const int swcol = ((tid & 7) ^ (srow0 & 7)) * 8;

    float4 rB0[8], rB1[8];

    auto LOADB = [&](int kk, float4* rB) {  // 8 VM ops
        const int k0 = kk * 64;
        #pragma unroll
        for (int j = 0; j < 4; ++j) {
            int row = srow0 + j * 32;
            const float* p = &We[(size_t)(nt * 128 + row) * HDIM + k0 + c8];
            rB[2*j]   = *reinterpret_cast<const float4*>(p);
            rB[2*j+1] = *reinterpret_cast<const float4*>(p + 4);
        }
    };
    auto STAGEA = [&](int kk, int buf) {    // 4 VM ops (gld_lds)
        const int k0 = kk * 64;
        #pragma unroll
        for (int j = 0; j < 4; ++j) {
            int row = srow0 + j * 32;
            gld_lds16(&Hin[(size_t)(tok0 + row) * HDIM + k0 + swcol],
                      &sA[buf][row][dcol]);
        }
    };
    auto WRITEB = [&](int buf, const float4* rB) {
        #pragma unroll
        for (int j = 0; j < 4; ++j) {
            int row = srow0 + j * 32;
            uint4 w;
            w.x = cvt_pk_bf16(rB[2*j].x,   rB[2*j].y);
            w.y = cvt_pk_bf16(rB[2*j].z,   rB[2*j].w);
            w.z = cvt_pk_bf16(rB[2*j+1].x, rB[2*j+1].y);
            w.w = cvt_pk_bf16(rB[2*j+1].z, rB[2*j+1].w);
            *reinterpret_cast<uint4*>(&sB[buf][row][swcol]) = w;
        }
    };
    auto COMPUTE = [&](int buf) {
        #pragma unroll
        for (int ks = 0; ks < 2; ++ks) {
            const int rc = (sw0 ^ (ks << 2)) << 3;
            bf16x8 a[4], b[4];
            #pragma unroll
            for (int m = 0; m < 4; ++m)
                a[m] = *reinterpret_cast<const bf16x8*>(&sA[buf][wr * 64 + m * 16 + lr][rc]);
            #pragma unroll
            for (int n = 0; n < 4; ++n)
                b[n] = *reinterpret_cast<const bf16x8*>(&sB[buf][wc * 64 + n * 16 + lr][rc]);
            #pragma unroll
            for (int m = 0; m < 4; ++m)
                #pragma unroll
                for (int n = 0; n < 4; ++n)
                    acc[m][n] = __builtin_amdgcn_mfma_f32_16x16x32_bf16(a[m], b[n], acc[m][n], 0, 0, 0);
        }
    };

    // ---- prologue
    LOADB(0, rB0);  SBAR();
    STAGEA(0, 0);   SBAR();
    LOADB(1, rB1);  SBAR();
    asm volatile("s_waitcnt vmcnt(12)" ::: "memory");  // LOADB(0) done
    SBAR();
    WRITEB(0, rB0); SBAR();
    asm volatile("s_waitcnt vmcnt(8) lgkmcnt(0)" ::: "memory");
    SBAR();
    __builtin_amdgcn_s_barrier();

    // ---- steady phases 0..5
    for (int t = 0; t < HDIM / 64 - 2; t += 2) {        // t = 0,2,4
        // phase t (buf 0)
        STAGEA(t + 1, 1);   SBAR();
        LOADB(t + 2, rB0);  SBAR();
        COMPUTE(0);
        asm volatile("s_waitcnt vmcnt(12)" ::: "memory");  // LOADB(t+1) -> rB1
        SBAR();
        WRITEB(1, rB1);     SBAR();
        asm volatile("s_waitcnt vmcnt(8) lgkmcnt(0)" ::: "memory");
        SBAR();
        __builtin_amdgcn_s_barrier();
        // phase t+1 (buf 1)
        STAGEA(t + 2, 0);   SBAR();
        LOADB(t + 3, rB1);  SBAR();
        COMPUTE(1);
        asm volatile("s_waitcnt vmcnt(12)" ::: "memory");  // LOADB(t+2) -> rB0
        SBAR();
        WRITEB(0, rB0);     SBAR();
        asm volatile("s_waitcnt vmcnt(8) lgkmcnt(0)" ::: "memory");
        SBAR();
        __builtin_amdgcn_s_barrier();
    }

    // ---- phase 6 (buf 0): leftover LOADB(7) in rB1
    STAGEA(7, 1);   SBAR();
    COMPUTE(0);
    asm volatile("s_waitcnt vmcnt(4)" ::: "memory");   // LOADB(7) done
    SBAR();
    WRITEB(1, rB1); SBAR();
    asm volatile("s_waitcnt vmcnt(0) lgkmcnt(0)" ::: "memory");
    SBAR();
    __builtin_amdgcn_s_barrier();
    // ---- phase 7 (buf 1)
    COMPUTE(1);

    const int dcol0 = nt * 128 + wc * 64;
    #pragma unroll
    for (int m = 0; m < 4; ++m) {
        #pragma unroll
        for (int n = 0; n < 4; ++n) {
            #pragma unroll
            for (int i = 0; i < 4; ++i) {
                int row = tok0 + wr * 64 + m * 16 + (lane >> 4) * 4 + i;
                int col = dcol0 + n * 16 + (lane & 15);
                Out[(size_t)row * DDIM + col] = acc[m][n][i];
            }
        }
    }
}

extern "C" void kernel_launch(void* const* d_in, const int* in_sizes, int n_in,
                              void* d_out, int out_size, void* d_ws, size_t ws_size,
                              hipStream_t stream) {
    const float* X   = (const float*)d_in[0];   // (T, D) fp32
    const float* S   = (const float*)d_in[1];   // (T, D/32) fp32
    const float* W13 = (const float*)d_in[4];   // (E, 2H, D) fp32
    const float* W2  = (const float*)d_in[5];   // (E, D, H) fp32
    float* Out = (float*)d_out;                 // (T, D) fp32

    // workspace: Hb bf16 (T*H) = 8 MiB.
    // Xb (T*D bf16 = 16 MiB) lives in d_out's first half: gemm1 consumes it,
    // then gemm2 overwrites all of d_out with the final fp32 output.
    __hip_bfloat16* Hb = (__hip_bfloat16*)d_ws;
    unsigned short* Xb = (unsigned short*)d_out;

    convert_x_kernel<<<2048, 256, 0, stream>>>(X, S, Xb);
    gemm1_silu_kernel<<<NE * 4 * 8, 512, 0, stream>>>(Xb, W13, Hb);
    gemm2_kernel<<<NE * 8 * 8, 256, 0, stream>>>(Hb, W2, Out);
}